// Round 4
// baseline (222.289 us; speedup 1.0000x reference)
//
#include <hip/hip_runtime.h>

// RoIAlign / crop-and-resize, TF2 half-pixel-center bilinear, POOL=7.
// fm: (256,256,512) fp32 NHWC; proposals: (N,4) int32 [x,y,w,h]; out: (N,7,7,512) fp32.
//
// R3: fused linear-warm + gather. Phase A: every block streams a contiguous
// grid-stride slice of fm (134 MB total) -> populates memory-side Infinity
// Cache at linear-burst HBM efficiency; reduction stored to d_ws to keep the
// loads alive. Phase B: the R1 row-gather (7 px per block, 28 independent
// loads) now hits L3 instead of issuing scattered 2KB HBM bursts.

constexpr int FW  = 256;   // feature map width
constexpr int FC  = 512;   // channels
constexpr int FC4 = FC / 4;
constexpr int FM_VEC4 = 256 * 256 * FC / 4;   // 8,388,608 float4s in fm

typedef float vfloat4 __attribute__((ext_vector_type(4)));

__device__ __forceinline__ void axis_coords(int start, int size, int p,
                                            int& c0, int& c1, float& frac) {
    // s = (p+0.5)*size/7 - 0.5, clipped to [0, size-1]; size >= 1 guaranteed.
    float s = ((float)p + 0.5f) * ((float)size / 7.0f) - 0.5f;
    s = fminf(fmaxf(s, 0.0f), (float)(size - 1));
    int i0 = (int)s;                 // s >= 0, truncation == floor
    int i1 = min(i0 + 1, size - 1);
    frac = s - (float)i0;
    c0 = start + i0;
    c1 = start + i1;
}

__global__ __launch_bounds__(128) void roi_align_warm_kernel(
        const float* __restrict__ fm,
        const int*   __restrict__ props,
        float*       __restrict__ out,
        float*       __restrict__ ws) {
    const int blk = blockIdx.x;               // n*7 + py
    const int tid = threadIdx.x;

    // ---- Phase A: linear warm sweep of fm (fills Infinity Cache) ----
    {
        const vfloat4* __restrict__ fmv = (const vfloat4*)fm;
        float acc = 0.0f;
        for (int i = blk * 128 + tid; i < FM_VEC4; i += gridDim.x * 128) {
            vfloat4 v = fmv[i];
            acc += v.x + v.y + v.z + v.w;
        }
        ws[blk * 128 + tid] = acc;            // keep the loads observable
    }

    // ---- Phase B: row gather ----
    const int n  = blk / 7;
    const int py = blk - n * 7;

    const int4 box = ((const int4*)props)[n]; // x, y, w, h

    int y0, y1;
    float fy;
    axis_coords(box.y, box.w, py, y0, y1, fy);
    const float gy = 1.0f - fy;

    int   x0[7], x1[7];
    float fx[7];
#pragma unroll
    for (int px = 0; px < 7; ++px)
        axis_coords(box.x, box.z, px, x0[px], x1[px], fx[px]);

    const vfloat4* __restrict__ r0 = (const vfloat4*)(fm + (size_t)y0 * FW * FC);
    const vfloat4* __restrict__ r1 = (const vfloat4*)(fm + (size_t)y1 * FW * FC);
    vfloat4* __restrict__ po = (vfloat4*)(out + ((size_t)n * 49 + (size_t)py * 7) * FC);

    const int c = tid;                        // 0..127 -> float4 lane (FC4 = 128)

    vfloat4 v00[7], v01[7], v10[7], v11[7];
#pragma unroll
    for (int px = 0; px < 7; ++px) {
        v00[px] = r0[x0[px] * FC4 + c];
        v01[px] = r0[x1[px] * FC4 + c];
        v10[px] = r1[x0[px] * FC4 + c];
        v11[px] = r1[x1[px] * FC4 + c];
    }

#pragma unroll
    for (int px = 0; px < 7; ++px) {
        const float fxp = fx[px], gxp = 1.0f - fx[px];
        vfloat4 top = v00[px] * gxp + v01[px] * fxp;
        vfloat4 bot = v10[px] * gxp + v11[px] * fxp;
        vfloat4 r   = top * gy + bot * fy;
        __builtin_nontemporal_store(r, &po[px * FC4 + c]);
    }
}

extern "C" void kernel_launch(void* const* d_in, const int* in_sizes, int n_in,
                              void* d_out, int out_size, void* d_ws, size_t ws_size,
                              hipStream_t stream) {
    const float* fm    = (const float*)d_in[0];
    const int*   props = (const int*)d_in[1];
    float*       out   = (float*)d_out;
    float*       ws    = (float*)d_ws;

    const int N = in_sizes[1] / 4;            // 512 proposals
    roi_align_warm_kernel<<<N * 7, 128, 0, stream>>>(fm, props, out, ws);
}

// Round 5
// 199.513 us; speedup vs baseline: 1.1142x; 1.1142x over previous
//
#include <hip/hip_runtime.h>

// RoIAlign / crop-and-resize, TF2 half-pixel-center bilinear, POOL=7.
// fm: (256,256,512) fp32 NHWC; proposals: (N,4) int32 [x,y,w,h]; out: (N,7,7,512) fp32.
//
// R4: gather-only (warm sweep reverted: +24us, no gather benefit -> gather is
// L2-miss-path bound, not HBM/L3-source bound). XCD-aware block swizzle:
// consecutive blockIdx round-robin across 8 XCDs, so map blockIdx%8 -> XCD
// partition and pack all 7 row-blocks of each box into the SAME XCD. The box's
// shared corner columns (x0/x1 identical across py) are then fetched into one
// L2 once instead of ~7 L2s, halving per-XCD EA traffic. nt stores keep the
// 52 MB output stream out of L2.

constexpr int FW  = 256;   // feature map width
constexpr int FC  = 512;   // channels
constexpr int FC4 = FC / 4;

typedef float vfloat4 __attribute__((ext_vector_type(4)));

__device__ __forceinline__ void axis_coords(int start, int size, int p,
                                            int& c0, int& c1, float& frac) {
    // s = (p+0.5)*size/7 - 0.5, clipped to [0, size-1]; size >= 1 guaranteed.
    float s = ((float)p + 0.5f) * ((float)size / 7.0f) - 0.5f;
    s = fminf(fmaxf(s, 0.0f), (float)(size - 1));
    int i0 = (int)s;                 // s >= 0, truncation == floor
    int i1 = min(i0 + 1, size - 1);
    frac = s - (float)i0;
    c0 = start + i0;
    c1 = start + i1;
}

__global__ __launch_bounds__(128) void roi_align_swz_kernel(
        const float* __restrict__ fm,
        const int*   __restrict__ props,
        float*       __restrict__ out,
        int boxes_per_xcd) {          // N/8
    // XCD swizzle: blocks with equal (blockIdx%8) are assumed to share an XCD.
    // Pack each box's 7 row-blocks into one XCD partition.
    const int B    = blockIdx.x;
    const int xcd  = B & 7;
    const int slot = B >> 3;                  // 0 .. N*7/8-1
    const int n    = xcd * boxes_per_xcd + slot / 7;
    const int py   = slot % 7;

    const int4 box = ((const int4*)props)[n]; // x, y, w, h

    int y0, y1;
    float fy;
    axis_coords(box.y, box.w, py, y0, y1, fy);
    const float gy = 1.0f - fy;

    int   x0[7], x1[7];
    float fx[7];
#pragma unroll
    for (int px = 0; px < 7; ++px)
        axis_coords(box.x, box.z, px, x0[px], x1[px], fx[px]);

    const vfloat4* __restrict__ r0 = (const vfloat4*)(fm + (size_t)y0 * FW * FC);
    const vfloat4* __restrict__ r1 = (const vfloat4*)(fm + (size_t)y1 * FW * FC);
    vfloat4* __restrict__ po = (vfloat4*)(out + ((size_t)n * 49 + (size_t)py * 7) * FC);

    const int c = threadIdx.x;                // 0..127 -> float4 lane (FC4 = 128)

    // 28 independent loads in flight per wave.
    vfloat4 v00[7], v01[7], v10[7], v11[7];
#pragma unroll
    for (int px = 0; px < 7; ++px) {
        v00[px] = r0[x0[px] * FC4 + c];
        v01[px] = r0[x1[px] * FC4 + c];
        v10[px] = r1[x0[px] * FC4 + c];
        v11[px] = r1[x1[px] * FC4 + c];
    }

#pragma unroll
    for (int px = 0; px < 7; ++px) {
        const float fxp = fx[px], gxp = 1.0f - fx[px];
        vfloat4 top = v00[px] * gxp + v01[px] * fxp;
        vfloat4 bot = v10[px] * gxp + v11[px] * fxp;
        vfloat4 r   = top * gy + bot * fy;
        __builtin_nontemporal_store(r, &po[px * FC4 + c]);
    }
}

// Fallback without swizzle for N not divisible by 8 (not hit here: N=512).
__global__ __launch_bounds__(128) void roi_align_row_kernel(
        const float* __restrict__ fm,
        const int*   __restrict__ props,
        float*       __restrict__ out) {
    const int blk = blockIdx.x;
    const int n   = blk / 7;
    const int py  = blk - n * 7;

    const int4 box = ((const int4*)props)[n];
    int y0, y1;
    float fy;
    axis_coords(box.y, box.w, py, y0, y1, fy);
    const float gy = 1.0f - fy;

    int   x0[7], x1[7];
    float fx[7];
#pragma unroll
    for (int px = 0; px < 7; ++px)
        axis_coords(box.x, box.z, px, x0[px], x1[px], fx[px]);

    const vfloat4* __restrict__ r0 = (const vfloat4*)(fm + (size_t)y0 * FW * FC);
    const vfloat4* __restrict__ r1 = (const vfloat4*)(fm + (size_t)y1 * FW * FC);
    vfloat4* __restrict__ po = (vfloat4*)(out + ((size_t)n * 49 + (size_t)py * 7) * FC);
    const int c = threadIdx.x;

    vfloat4 v00[7], v01[7], v10[7], v11[7];
#pragma unroll
    for (int px = 0; px < 7; ++px) {
        v00[px] = r0[x0[px] * FC4 + c];
        v01[px] = r0[x1[px] * FC4 + c];
        v10[px] = r1[x0[px] * FC4 + c];
        v11[px] = r1[x1[px] * FC4 + c];
    }
#pragma unroll
    for (int px = 0; px < 7; ++px) {
        const float fxp = fx[px], gxp = 1.0f - fx[px];
        vfloat4 top = v00[px] * gxp + v01[px] * fxp;
        vfloat4 bot = v10[px] * gxp + v11[px] * fxp;
        vfloat4 r   = top * gy + bot * fy;
        __builtin_nontemporal_store(r, &po[px * FC4 + c]);
    }
}

extern "C" void kernel_launch(void* const* d_in, const int* in_sizes, int n_in,
                              void* d_out, int out_size, void* d_ws, size_t ws_size,
                              hipStream_t stream) {
    const float* fm    = (const float*)d_in[0];
    const int*   props = (const int*)d_in[1];
    float*       out   = (float*)d_out;

    const int N = in_sizes[1] / 4;            // 512 proposals
    if (N % 8 == 0) {
        roi_align_swz_kernel<<<N * 7, 128, 0, stream>>>(fm, props, out, N / 8);
    } else {
        roi_align_row_kernel<<<N * 7, 128, 0, stream>>>(fm, props, out);
    }
}